// Round 2
// baseline (551.717 us; speedup 1.0000x reference)
//
#include <hip/hip_runtime.h>
#include <hip/hip_bf16.h>

// ---------------- graph prep kernels ----------------

__global__ void k_zero2(int* __restrict__ a, int* __restrict__ b, int n) {
  int i = blockIdx.x * 256 + threadIdx.x;
  if (i < n) { a[i] = 0; b[i] = 0; }
}

__global__ void k_count(const int* __restrict__ ei, int* __restrict__ deg, int E) {
  int e = blockIdx.x * 256 + threadIdx.x;
  if (e < E) atomicAdd(&deg[ei[E + e]], 1);
}

__global__ void k_dinv(const int* __restrict__ deg, float* __restrict__ dinv, int n) {
  int i = blockIdx.x * 256 + threadIdx.x;
  if (i < n) dinv[i] = rsqrtf((float)(deg[i] + 1));   // +1 = self-loop
}

// exclusive scan, stage 1: per-block scan + block sums
__global__ void k_scan1(const int* __restrict__ deg, int* __restrict__ excl,
                        int* __restrict__ bsums, int n) {
  __shared__ int s[256];
  int t = threadIdx.x;
  int i = blockIdx.x * 256 + t;
  int v = (i < n) ? deg[i] : 0;
  s[t] = v;
  __syncthreads();
  for (int off = 1; off < 256; off <<= 1) {
    int add = (t >= off) ? s[t - off] : 0;
    __syncthreads();
    s[t] += add;
    __syncthreads();
  }
  if (i < n) excl[i] = s[t] - v;
  if (t == 255) bsums[blockIdx.x] = s[255];
}

// stage 2: scan the block sums (single block, nb <= 512)
__global__ void k_scan2(int* __restrict__ bsums, int nb) {
  __shared__ int s[512];
  int t = threadIdx.x;
  int v = (t < nb) ? bsums[t] : 0;
  s[t] = v;
  __syncthreads();
  for (int off = 1; off < 512; off <<= 1) {
    int add = (t >= off) ? s[t - off] : 0;
    __syncthreads();
    s[t] += add;
    __syncthreads();
  }
  if (t < nb) bsums[t] = s[t] - v;   // exclusive block offsets
}

// stage 3: add block offsets
__global__ void k_scan3(int* __restrict__ rowstart, const int* __restrict__ bsums, int n) {
  int i = blockIdx.x * 256 + threadIdx.x;
  if (i < n) rowstart[i] += bsums[blockIdx.x];
}

__global__ void k_fill(const int* __restrict__ ei, const int* __restrict__ rowstart,
                       int* __restrict__ fill, int* __restrict__ csr, int E) {
  int e = blockIdx.x * 256 + threadIdx.x;
  if (e < E) {
    int d = ei[E + e];
    int pos = rowstart[d] + atomicAdd(&fill[d], 1);
    csr[pos] = ei[e];
  }
}

// ---------------- GEMM: G[i,:] = (X[i,:] @ W) * dinv[i] ----------------
// Block: 256 threads = 16x16 thread grid; tile 128 rows x NT cols.
// Per-thread register tile: 8 rows x (NT/16) cols. K staged in LDS, KT=16.
template <int NT>
__global__ __launch_bounds__(256) void gemm_scale(
    const float* __restrict__ X, const float* __restrict__ W,
    const float* __restrict__ dinv, float* __restrict__ G, int nrows) {
  constexpr int TN4 = NT / 64;   // f4 cols per thread: 2 (NT=128) or 1 (NT=64)
  constexpr int KT = 16;
  constexpr int NW4 = NT / 4;    // W row length in float4
  __shared__ float4 Xs[128 * 4];       // [row][k/4], row stride = 4 f4 (16 floats)
  __shared__ float4 Ws[KT * NW4];      // [k][col/4]
  const float4* X4 = (const float4*)X;
  const float4* W4 = (const float4*)W;
  int tid = threadIdx.x;
  int tx = tid & 15, ty = tid >> 4;
  int row0 = blockIdx.x * 128;

  float acc[8][TN4][4];
#pragma unroll
  for (int r = 0; r < 8; ++r)
#pragma unroll
    for (int c = 0; c < TN4; ++c)
#pragma unroll
      for (int q = 0; q < 4; ++q) acc[r][c][q] = 0.f;

  for (int k0 = 0; k0 < 128; k0 += KT) {
    // stage X tile: 128 rows x 16 k = 512 f4, 2 per thread
#pragma unroll
    for (int u = 0; u < 2; ++u) {
      int f = tid + u * 256;
      int r = f >> 2, kq = f & 3;
      int gr = row0 + r;
      float4 v = {0.f, 0.f, 0.f, 0.f};
      if (gr < nrows) v = X4[gr * 32 + (k0 >> 2) + kq];
      Xs[r * 4 + kq] = v;
    }
    // stage W tile: KT x NT
#pragma unroll
    for (int u = 0; u < (KT * NW4) / 256; ++u) {
      int f = tid + u * 256;
      int k = f / NW4, c = f % NW4;
      Ws[f] = W4[(size_t)(k0 + k) * NW4 + c];
    }
    __syncthreads();
#pragma unroll
    for (int k4 = 0; k4 < KT / 4; ++k4) {
      float4 xa[8];
#pragma unroll
      for (int r = 0; r < 8; ++r) xa[r] = Xs[(ty * 8 + r) * 4 + k4];
      float4 wv[4][TN4];
#pragma unroll
      for (int kk = 0; kk < 4; ++kk)
#pragma unroll
        for (int c = 0; c < TN4; ++c)
          wv[kk][c] = Ws[(k4 * 4 + kk) * NW4 + tx * TN4 + c];
#pragma unroll
      for (int r = 0; r < 8; ++r) {
        float xk[4] = {xa[r].x, xa[r].y, xa[r].z, xa[r].w};
#pragma unroll
        for (int kk = 0; kk < 4; ++kk)
#pragma unroll
          for (int c = 0; c < TN4; ++c) {
            acc[r][c][0] = fmaf(xk[kk], wv[kk][c].x, acc[r][c][0]);
            acc[r][c][1] = fmaf(xk[kk], wv[kk][c].y, acc[r][c][1]);
            acc[r][c][2] = fmaf(xk[kk], wv[kk][c].z, acc[r][c][2]);
            acc[r][c][3] = fmaf(xk[kk], wv[kk][c].w, acc[r][c][3]);
          }
      }
    }
    __syncthreads();
  }
  // epilogue: scale by dinv[row], store
  float4* G4 = (float4*)G;
#pragma unroll
  for (int r = 0; r < 8; ++r) {
    int gr = row0 + ty * 8 + r;
    if (gr < nrows) {
      float d = dinv[gr];
#pragma unroll
      for (int c = 0; c < TN4; ++c) {
        float4 o = {acc[r][c][0] * d, acc[r][c][1] * d, acc[r][c][2] * d,
                    acc[r][c][3] * d};
        G4[(size_t)gr * NW4 + tx * TN4 + c] = o;
      }
    }
  }
}

// ---------------- aggregation: out[i] = relu(dinv[i]*(g[i]+sum g[src]) + b) ---

// 128-wide rows, fp32 out. One wave per node, float2 per lane.
__global__ __launch_bounds__(256) void agg128(
    const float* __restrict__ G, const int* __restrict__ csr,
    const int* __restrict__ rowstart, const int* __restrict__ deg,
    const float* __restrict__ dinv, const float* __restrict__ bias,
    float* __restrict__ out, int n) {
  int wid = blockIdx.x * 4 + (threadIdx.x >> 6);
  if (wid >= n) return;
  int i = __builtin_amdgcn_readfirstlane(wid);
  int lane = threadIdx.x & 63;
  const float2* Gp = (const float2*)G;
  float2 a = Gp[(size_t)i * 64 + lane];   // self-loop term
  int s = rowstart[i];
  int e = s + deg[i];
  int j = s;
  for (; j + 1 < e; j += 2) {
    int s0 = csr[j], s1 = csr[j + 1];
    float2 v0 = Gp[(size_t)s0 * 64 + lane];
    float2 v1 = Gp[(size_t)s1 * 64 + lane];
    a.x += v0.x + v1.x;
    a.y += v0.y + v1.y;
  }
  if (j < e) {
    float2 v0 = Gp[(size_t)csr[j] * 64 + lane];
    a.x += v0.x;
    a.y += v0.y;
  }
  float d = dinv[i];
  float2 b = ((const float2*)bias)[lane];
  float2 o;
  o.x = fmaxf(fmaf(d, a.x, b.x), 0.f);
  o.y = fmaxf(fmaf(d, a.y, b.y), 0.f);
  ((float2*)out)[(size_t)i * 64 + lane] = o;
}

// 64-wide rows, fp32 out. One wave per node, 1 float per lane.
__global__ __launch_bounds__(256) void agg64(
    const float* __restrict__ G, const int* __restrict__ csr,
    const int* __restrict__ rowstart, const int* __restrict__ deg,
    const float* __restrict__ dinv, const float* __restrict__ bias,
    float* __restrict__ out, int n) {
  int wid = blockIdx.x * 4 + (threadIdx.x >> 6);
  if (wid >= n) return;
  int i = __builtin_amdgcn_readfirstlane(wid);
  int lane = threadIdx.x & 63;
  float a = G[(size_t)i * 64 + lane];   // self-loop term
  int s = rowstart[i];
  int e = s + deg[i];
  int j = s;
  for (; j + 1 < e; j += 2) {
    int s0 = csr[j], s1 = csr[j + 1];
    a += G[(size_t)s0 * 64 + lane] + G[(size_t)s1 * 64 + lane];
  }
  if (j < e) a += G[(size_t)csr[j] * 64 + lane];
  float o = fmaxf(fmaf(dinv[i], a, bias[lane]), 0.f);
  out[(size_t)i * 64 + lane] = o;   // fp32 output (reference output dtype is float32)
}

// ---------------- launch ----------------

extern "C" void kernel_launch(void* const* d_in, const int* in_sizes, int n_in,
                              void* d_out, int out_size, void* d_ws, size_t ws_size,
                              hipStream_t stream) {
  const float* x  = (const float*)d_in[0];
  const int*   ei = (const int*)d_in[1];
  const float* W1 = (const float*)d_in[2];
  const float* b1 = (const float*)d_in[3];
  const float* W2 = (const float*)d_in[4];
  const float* b2 = (const float*)d_in[5];
  float* out = (float*)d_out;

  const int N = in_sizes[0] / 128;
  const int E = in_sizes[1] / 2;

  char* base = (char*)d_ws;
  size_t off = 0;
  auto alloc = [&](size_t bytes) -> void* {
    void* p = base + off;
    off += (bytes + 255) & ~(size_t)255;
    return p;
  };
  int*   deg      = (int*)alloc((size_t)N * 4);
  int*   fill     = (int*)alloc((size_t)N * 4);
  int*   rowstart = (int*)alloc((size_t)N * 4);
  int*   bsums    = (int*)alloc(512 * 4);
  float* dinv     = (float*)alloc((size_t)N * 4);
  int*   csr      = (int*)alloc((size_t)E * 4);
  float* g1       = (float*)alloc((size_t)N * 128 * 4);  // also reused as g2
  float* x2       = (float*)alloc((size_t)N * 128 * 4);

  int nbN = (N + 255) / 256;
  int nbE = (E + 255) / 256;

  k_zero2<<<nbN, 256, 0, stream>>>(deg, fill, N);
  k_count<<<nbE, 256, 0, stream>>>(ei, deg, E);
  k_dinv<<<nbN, 256, 0, stream>>>(deg, dinv, N);
  k_scan1<<<nbN, 256, 0, stream>>>(deg, rowstart, bsums, N);
  k_scan2<<<1, 512, 0, stream>>>(bsums, nbN);
  k_scan3<<<nbN, 256, 0, stream>>>(rowstart, bsums, N);
  k_fill<<<nbE, 256, 0, stream>>>(ei, rowstart, fill, csr, E);

  int gblk = (N + 127) / 128;
  gemm_scale<128><<<gblk, 256, 0, stream>>>(x, W1, dinv, g1, N);
  agg128<<<(N + 3) / 4, 256, 0, stream>>>(g1, csr, rowstart, deg, dinv, b1, x2, N);
  gemm_scale<64><<<gblk, 256, 0, stream>>>(x2, W2, dinv, g1, N);
  agg64<<<(N + 3) / 4, 256, 0, stream>>>(g1, csr, rowstart, deg, dinv, b2, out, N);
}

// Round 3
// 375.157 us; speedup vs baseline: 1.4706x; 1.4706x over previous
//
#include <hip/hip_runtime.h>
#include <hip/hip_bf16.h>
#include <hip/hip_fp16.h>

// ================= bucketed CSR build =================
// Buckets of 512 dst nodes: NB = ceil(N/512) (=196 for N=100k, must be <=256).
// passA: global bucket histogram (LDS-reduced)
// scanB: exclusive scan of bucket counts -> bstart, bfill (1 block)
// passB: scatter (dst,src) pairs into bucket regions, per-block reservations
// passC: per-bucket LDS count/scan/fill -> rowstart, deg, dinv, csr

#define BSH 9
#define BSZ 512
#define CAP 12288   // max edges per bucket staged in LDS (mean 8192, 45 sigma)

__global__ __launch_bounds__(256) void passA(const int* __restrict__ ei,
                                             int* __restrict__ bcount, int E, int NB) {
  __shared__ int hist[256];
  int t = threadIdx.x;
  hist[t] = 0;
  __syncthreads();
  for (int e = blockIdx.x * 256 + t; e < E; e += gridDim.x * 256)
    atomicAdd(&hist[ei[E + e] >> BSH], 1);
  __syncthreads();
  if (t < NB && hist[t]) atomicAdd(&bcount[t], hist[t]);
}

__global__ __launch_bounds__(256) void scanB(const int* __restrict__ bcount,
                                             int* __restrict__ bstart,
                                             int* __restrict__ bfill, int NB, int E) {
  __shared__ int s[256];
  int t = threadIdx.x;
  int v = (t < NB) ? bcount[t] : 0;
  s[t] = v;
  __syncthreads();
  for (int off = 1; off < 256; off <<= 1) {
    int add = (t >= off) ? s[t - off] : 0;
    __syncthreads();
    s[t] += add;
    __syncthreads();
  }
  if (t < NB) {
    int ex = s[t] - v;
    bstart[t] = ex;
    bfill[t] = ex;
  }
  if (t == 0) bstart[NB] = E;
}

__global__ __launch_bounds__(256) void passB(const int* __restrict__ ei,
                                             int* __restrict__ bfill,
                                             int2* __restrict__ pairs, int E) {
  __shared__ int hist[256];
  __shared__ int gbase[256];
  int t = threadIdx.x;
  hist[t] = 0;
  __syncthreads();
  int d[8], s[8], lp[8], bb[8];
  int base = blockIdx.x * 2048;
#pragma unroll
  for (int u = 0; u < 8; ++u) {
    int e = base + u * 256 + t;
    if (e < E) {
      d[u] = ei[E + e];
      s[u] = ei[e];
      bb[u] = d[u] >> BSH;
      lp[u] = atomicAdd(&hist[bb[u]], 1);
    } else {
      bb[u] = -1;
    }
  }
  __syncthreads();
  if (hist[t]) gbase[t] = atomicAdd(&bfill[t], hist[t]);
  __syncthreads();
#pragma unroll
  for (int u = 0; u < 8; ++u)
    if (bb[u] >= 0) pairs[gbase[bb[u]] + lp[u]] = make_int2(d[u], s[u]);
}

__global__ __launch_bounds__(256) void passC(const int2* __restrict__ pairs,
                                             const int* __restrict__ bstart,
                                             int* __restrict__ rowstart,
                                             int* __restrict__ deg,
                                             float* __restrict__ dinv,
                                             int* __restrict__ csr, int N) {
  __shared__ int hcnt[BSZ];
  __shared__ int lfill[BSZ];
  __shared__ int ss[256];
  __shared__ int lcsr[CAP];
  int b = blockIdx.x;
  int t = threadIdx.x;
  int lo = bstart[b], hi = bstart[b + 1];
  int cnt = hi - lo;
  int nbase = b << BSH;
  hcnt[t] = 0;
  hcnt[t + 256] = 0;
  __syncthreads();
  for (int k = lo + t; k < hi; k += 256)
    atomicAdd(&hcnt[pairs[k].x - nbase], 1);
  __syncthreads();
  // exclusive scan of hcnt[512] with 256 threads (2 elems/thread)
  int a0 = hcnt[2 * t], a1 = hcnt[2 * t + 1];
  int sum = a0 + a1;
  ss[t] = sum;
  __syncthreads();
  for (int off = 1; off < 256; off <<= 1) {
    int add = (t >= off) ? ss[t - off] : 0;
    __syncthreads();
    ss[t] += add;
    __syncthreads();
  }
  int ex = ss[t] - sum;
  lfill[2 * t] = ex;
  lfill[2 * t + 1] = ex + a0;
  int d0 = nbase + 2 * t, d1 = d0 + 1;
  if (d0 < N) {
    rowstart[d0] = lo + ex;
    deg[d0] = a0;
    dinv[d0] = rsqrtf((float)(a0 + 1));
  }
  if (d1 < N) {
    rowstart[d1] = lo + ex + a0;
    deg[d1] = a1;
    dinv[d1] = rsqrtf((float)(a1 + 1));
  }
  __syncthreads();
  bool fits = (cnt <= CAP);
  for (int k = lo + t; k < hi; k += 256) {
    int2 p = pairs[k];
    int pos = atomicAdd(&lfill[p.x - nbase], 1);
    if (fits) lcsr[pos] = p.y;
    else      csr[lo + pos] = p.y;
  }
  __syncthreads();
  if (fits)
    for (int k = t; k < cnt; k += 256) csr[lo + k] = lcsr[k];
}

// ============ GEMM: G[i,:] = (X[i,:] @ W) * dinv[i], fp16 out ============
// 256 threads = 16x16; tile 128 rows x NT cols; per-thread 8 x (NT/16).
template <int NT, bool IN_F16>
__global__ __launch_bounds__(256) void gemm_scale(
    const void* __restrict__ Xv, const float* __restrict__ W,
    const float* __restrict__ dinv, __half* __restrict__ G, int nrows) {
  constexpr int TN4 = NT / 64;
  constexpr int KT = 16;
  constexpr int NW4 = NT / 4;
  __shared__ float4 Xs[128 * 4];   // [row][k/4]
  __shared__ float4 Ws[KT * NW4];  // [k][col/4]
  const float4* W4 = (const float4*)W;
  int tid = threadIdx.x;
  int tx = tid & 15, ty = tid >> 4;
  int row0 = blockIdx.x * 128;

  float acc[8][TN4][4];
#pragma unroll
  for (int r = 0; r < 8; ++r)
#pragma unroll
    for (int c = 0; c < TN4; ++c)
#pragma unroll
      for (int q = 0; q < 4; ++q) acc[r][c][q] = 0.f;

  for (int k0 = 0; k0 < 128; k0 += KT) {
    if constexpr (!IN_F16) {
      const float4* X4 = (const float4*)Xv;
#pragma unroll
      for (int u = 0; u < 2; ++u) {
        int f = tid + u * 256;
        int r = f >> 2, kq = f & 3;
        int gr = row0 + r;
        float4 v = {0.f, 0.f, 0.f, 0.f};
        if (gr < nrows) v = X4[gr * 32 + (k0 >> 2) + kq];
        Xs[r * 4 + kq] = v;
      }
    } else {
      const float4* X4h = (const float4*)Xv;  // 8 halves per float4
      int r = tid >> 1, oct = tid & 1;
      int gr = row0 + r;
      float4 raw = {0.f, 0.f, 0.f, 0.f};
      if (gr < nrows) raw = X4h[gr * 16 + (k0 >> 3) + oct];
      const __half2* hp = (const __half2*)&raw;
      float2 f0 = __half22float2(hp[0]);
      float2 f1 = __half22float2(hp[1]);
      float2 f2 = __half22float2(hp[2]);
      float2 f3 = __half22float2(hp[3]);
      Xs[r * 4 + oct * 2 + 0] = make_float4(f0.x, f0.y, f1.x, f1.y);
      Xs[r * 4 + oct * 2 + 1] = make_float4(f2.x, f2.y, f3.x, f3.y);
    }
#pragma unroll
    for (int u = 0; u < (KT * NW4) / 256; ++u) {
      int f = tid + u * 256;
      int k = f / NW4, c = f % NW4;
      Ws[f] = W4[(size_t)(k0 + k) * NW4 + c];
    }
    __syncthreads();
#pragma unroll
    for (int k4 = 0; k4 < KT / 4; ++k4) {
      float4 xa[8];
#pragma unroll
      for (int r = 0; r < 8; ++r) xa[r] = Xs[(ty * 8 + r) * 4 + k4];
      float4 wv[4][TN4];
#pragma unroll
      for (int kk = 0; kk < 4; ++kk)
#pragma unroll
        for (int c = 0; c < TN4; ++c)
          wv[kk][c] = Ws[(k4 * 4 + kk) * NW4 + tx * TN4 + c];
#pragma unroll
      for (int r = 0; r < 8; ++r) {
        float xk[4] = {xa[r].x, xa[r].y, xa[r].z, xa[r].w};
#pragma unroll
        for (int kk = 0; kk < 4; ++kk)
#pragma unroll
          for (int c = 0; c < TN4; ++c) {
            acc[r][c][0] = fmaf(xk[kk], wv[kk][c].x, acc[r][c][0]);
            acc[r][c][1] = fmaf(xk[kk], wv[kk][c].y, acc[r][c][1]);
            acc[r][c][2] = fmaf(xk[kk], wv[kk][c].z, acc[r][c][2]);
            acc[r][c][3] = fmaf(xk[kk], wv[kk][c].w, acc[r][c][3]);
          }
      }
    }
    __syncthreads();
  }
  float2* G2 = (float2*)G;   // 4 halves per float2
#pragma unroll
  for (int r = 0; r < 8; ++r) {
    int gr = row0 + ty * 8 + r;
    if (gr < nrows) {
      float d = dinv[gr];
#pragma unroll
      for (int c = 0; c < TN4; ++c) {
        union { __half2 h[2]; float2 f; } u;
        u.h[0] = __floats2half2_rn(acc[r][c][0] * d, acc[r][c][1] * d);
        u.h[1] = __floats2half2_rn(acc[r][c][2] * d, acc[r][c][3] * d);
        G2[(size_t)gr * (NT / 4) + tx * TN4 + c] = u.f;
      }
    }
  }
}

// ===== aggregation: out[i] = relu(dinv[i]*(g[i]+sum g[src]) + b) =====

// 128-wide fp16 rows, fp16 out. One wave per node, half2 per lane.
__global__ __launch_bounds__(256) void agg128(
    const __half* __restrict__ G, const int* __restrict__ csr,
    const int* __restrict__ rowstart, const int* __restrict__ deg,
    const float* __restrict__ dinv, const float* __restrict__ bias,
    __half* __restrict__ out, int n) {
  int wid = blockIdx.x * 4 + (threadIdx.x >> 6);
  if (wid >= n) return;
  int i = __builtin_amdgcn_readfirstlane(wid);
  int lane = threadIdx.x & 63;
  const __half2* Gp = (const __half2*)G;
  float2 a = __half22float2(Gp[(size_t)i * 64 + lane]);  // self-loop
  int s = rowstart[i];
  int e = s + deg[i];
  int j = s;
  for (; j + 1 < e; j += 2) {
    int s0 = csr[j], s1 = csr[j + 1];
    float2 v0 = __half22float2(Gp[(size_t)s0 * 64 + lane]);
    float2 v1 = __half22float2(Gp[(size_t)s1 * 64 + lane]);
    a.x += v0.x + v1.x;
    a.y += v0.y + v1.y;
  }
  if (j < e) {
    float2 v0 = __half22float2(Gp[(size_t)csr[j] * 64 + lane]);
    a.x += v0.x;
    a.y += v0.y;
  }
  float d = dinv[i];
  float2 b = ((const float2*)bias)[lane];
  float ox = fmaxf(fmaf(d, a.x, b.x), 0.f);
  float oy = fmaxf(fmaf(d, a.y, b.y), 0.f);
  ((__half2*)out)[(size_t)i * 64 + lane] = __floats2half2_rn(ox, oy);
}

// 64-wide fp16 rows, fp32 out. One wave per node, 1 half per lane.
__global__ __launch_bounds__(256) void agg64(
    const __half* __restrict__ G, const int* __restrict__ csr,
    const int* __restrict__ rowstart, const int* __restrict__ deg,
    const float* __restrict__ dinv, const float* __restrict__ bias,
    float* __restrict__ out, int n) {
  int wid = blockIdx.x * 4 + (threadIdx.x >> 6);
  if (wid >= n) return;
  int i = __builtin_amdgcn_readfirstlane(wid);
  int lane = threadIdx.x & 63;
  float a = __half2float(G[(size_t)i * 64 + lane]);  // self-loop
  int s = rowstart[i];
  int e = s + deg[i];
  int j = s;
  for (; j + 1 < e; j += 2) {
    int s0 = csr[j], s1 = csr[j + 1];
    a += __half2float(G[(size_t)s0 * 64 + lane]) +
         __half2float(G[(size_t)s1 * 64 + lane]);
  }
  if (j < e) a += __half2float(G[(size_t)csr[j] * 64 + lane]);
  float o = fmaxf(fmaf(dinv[i], a, bias[lane]), 0.f);
  out[(size_t)i * 64 + lane] = o;
}

// ================= launch =================

extern "C" void kernel_launch(void* const* d_in, const int* in_sizes, int n_in,
                              void* d_out, int out_size, void* d_ws, size_t ws_size,
                              hipStream_t stream) {
  const float* x  = (const float*)d_in[0];
  const int*   ei = (const int*)d_in[1];
  const float* W1 = (const float*)d_in[2];
  const float* b1 = (const float*)d_in[3];
  const float* W2 = (const float*)d_in[4];
  const float* b2 = (const float*)d_in[5];
  float* out = (float*)d_out;

  const int N = in_sizes[0] / 128;
  const int E = in_sizes[1] / 2;
  const int NB = (N + BSZ - 1) >> BSH;   // 196 for N=100k

  char* base = (char*)d_ws;
  size_t off = 0;
  auto alloc = [&](size_t bytes) -> void* {
    void* p = base + off;
    off += (bytes + 255) & ~(size_t)255;
    return p;
  };
  int*    bcount   = (int*)alloc(256 * 4);
  int*    bstart   = (int*)alloc(260 * 4);
  int*    bfill    = (int*)alloc(256 * 4);
  int*    deg      = (int*)alloc((size_t)N * 4);
  int*    rowstart = (int*)alloc((size_t)N * 4);
  float*  dinv     = (float*)alloc((size_t)N * 4);
  int*    csr      = (int*)alloc((size_t)E * 4);
  int2*   pairs    = (int2*)alloc((size_t)E * 8);
  __half* g1       = (__half*)alloc((size_t)N * 128 * 2);  // reused for g2
  __half* x2       = (__half*)alloc((size_t)N * 128 * 2);

  hipMemsetAsync(bcount, 0, 256 * 4, stream);
  passA<<<512, 256, 0, stream>>>(ei, bcount, E, NB);
  scanB<<<1, 256, 0, stream>>>(bcount, bstart, bfill, NB, E);
  passB<<<(E + 2047) / 2048, 256, 0, stream>>>(ei, bfill, pairs, E);
  passC<<<NB, 256, 0, stream>>>(pairs, bstart, rowstart, deg, dinv, csr, N);

  int gblk = (N + 127) / 128;
  gemm_scale<128, false><<<gblk, 256, 0, stream>>>(x, W1, dinv, g1, N);
  agg128<<<(N + 3) / 4, 256, 0, stream>>>(g1, csr, rowstart, deg, dinv, b1, x2, N);
  gemm_scale<64, true><<<gblk, 256, 0, stream>>>(x2, W2, dinv, g1, N);
  agg64<<<(N + 3) / 4, 256, 0, stream>>>(g1, csr, rowstart, deg, dinv, b2, out, N);
}

// Round 4
// 325.612 us; speedup vs baseline: 1.6944x; 1.1522x over previous
//
#include <hip/hip_runtime.h>
#include <hip/hip_fp16.h>

// ================= bucketed CSR build =================
#define BSH 9
#define BSZ 512
#define CAP 12288   // max edges per bucket staged in LDS (mean 8192)

__global__ __launch_bounds__(256) void passA(const int* __restrict__ ei,
                                             int* __restrict__ bcount, int E, int NB) {
  __shared__ int hist[256];
  int t = threadIdx.x;
  hist[t] = 0;
  __syncthreads();
  for (int e = blockIdx.x * 256 + t; e < E; e += gridDim.x * 256)
    atomicAdd(&hist[ei[E + e] >> BSH], 1);
  __syncthreads();
  if (t < NB && hist[t]) atomicAdd(&bcount[t], hist[t]);
}

__global__ __launch_bounds__(256) void scanB(const int* __restrict__ bcount,
                                             int* __restrict__ bstart,
                                             int* __restrict__ bfill, int NB, int E) {
  __shared__ int s[256];
  int t = threadIdx.x;
  int v = (t < NB) ? bcount[t] : 0;
  s[t] = v;
  __syncthreads();
  for (int off = 1; off < 256; off <<= 1) {
    int add = (t >= off) ? s[t - off] : 0;
    __syncthreads();
    s[t] += add;
    __syncthreads();
  }
  if (t < NB) {
    int ex = s[t] - v;
    bstart[t] = ex;
    bfill[t] = ex;
  }
  if (t == 0) bstart[NB] = E;
}

// ============ GEMM body: G[i,:] = (X[i,:] @ W) [* dinv[i]] -> fp16 ============
template <int NT, bool IN_F16, bool SCALE>
__device__ __forceinline__ void gemm_body(const void* __restrict__ Xv,
                                          const float* __restrict__ W,
                                          const float* __restrict__ dinv,
                                          __half* __restrict__ G, int nrows, int bid,
                                          float4* Xs, float4* Ws) {
  constexpr int TN4 = NT / 64;
  constexpr int KT = 16;
  constexpr int NW4 = NT / 4;
  const float4* W4 = (const float4*)W;
  int tid = threadIdx.x;
  int tx = tid & 15, ty = (tid >> 4) & 3;   // ty 0..3 within wave group pattern
  int tyg = tid >> 4;                       // 0..15 row-group id
  int row0 = bid * 128;

  float acc[8][TN4][4];
#pragma unroll
  for (int r = 0; r < 8; ++r)
#pragma unroll
    for (int c = 0; c < TN4; ++c)
#pragma unroll
      for (int q = 0; q < 4; ++q) acc[r][c][q] = 0.f;

  for (int k0 = 0; k0 < 128; k0 += KT) {
    if constexpr (!IN_F16) {
      const float4* X4 = (const float4*)Xv;
#pragma unroll
      for (int u = 0; u < 2; ++u) {
        int f = tid + u * 256;
        int r = f >> 2, kq = f & 3;
        int gr = row0 + r;
        float4 v = {0.f, 0.f, 0.f, 0.f};
        if (gr < nrows) v = X4[gr * 32 + (k0 >> 2) + kq];
        Xs[r * 4 + kq] = v;
      }
    } else {
      const float4* X4h = (const float4*)Xv;  // 8 halves per float4
      int r = tid >> 1, oct = tid & 1;
      int gr = row0 + r;
      float4 raw = {0.f, 0.f, 0.f, 0.f};
      if (gr < nrows) raw = X4h[gr * 16 + (k0 >> 3) + oct];
      const __half2* hp = (const __half2*)&raw;
      float2 f0 = __half22float2(hp[0]);
      float2 f1 = __half22float2(hp[1]);
      float2 f2 = __half22float2(hp[2]);
      float2 f3 = __half22float2(hp[3]);
      Xs[r * 4 + oct * 2 + 0] = make_float4(f0.x, f0.y, f1.x, f1.y);
      Xs[r * 4 + oct * 2 + 1] = make_float4(f2.x, f2.y, f3.x, f3.y);
    }
#pragma unroll
    for (int u = 0; u < (KT * NW4 + 255) / 256; ++u) {
      int f = tid + u * 256;
      if (f < KT * NW4) {
        int k = f / NW4, c = f % NW4;
        Ws[f] = W4[(size_t)(k0 + k) * NW4 + c];
      }
    }
    __syncthreads();
#pragma unroll
    for (int k4 = 0; k4 < KT / 4; ++k4) {
      int kk4 = (k4 + ty) & 3;   // swizzle: each ty-group reads different k-col
      float4 xa[8];
#pragma unroll
      for (int r = 0; r < 8; ++r) xa[r] = Xs[(tyg * 8 + r) * 4 + kk4];
      float4 wv[4][TN4];
#pragma unroll
      for (int kk = 0; kk < 4; ++kk)
#pragma unroll
        for (int c = 0; c < TN4; ++c)
          wv[kk][c] = Ws[(kk4 * 4 + kk) * NW4 + tx * TN4 + c];
#pragma unroll
      for (int r = 0; r < 8; ++r) {
        float xk[4] = {xa[r].x, xa[r].y, xa[r].z, xa[r].w};
#pragma unroll
        for (int kk = 0; kk < 4; ++kk)
#pragma unroll
          for (int c = 0; c < TN4; ++c) {
            acc[r][c][0] = fmaf(xk[kk], wv[kk][c].x, acc[r][c][0]);
            acc[r][c][1] = fmaf(xk[kk], wv[kk][c].y, acc[r][c][1]);
            acc[r][c][2] = fmaf(xk[kk], wv[kk][c].z, acc[r][c][2]);
            acc[r][c][3] = fmaf(xk[kk], wv[kk][c].w, acc[r][c][3]);
          }
      }
    }
    __syncthreads();
  }
  float2* G2 = (float2*)G;   // 4 halves per float2
#pragma unroll
  for (int r = 0; r < 8; ++r) {
    int gr = row0 + tyg * 8 + r;
    if (gr < nrows) {
      float d = SCALE ? dinv[gr] : 1.f;
#pragma unroll
      for (int c = 0; c < TN4; ++c) {
        union { __half2 h[2]; float2 f; } u;
        u.h[0] = __floats2half2_rn(acc[r][c][0] * d, acc[r][c][1] * d);
        u.h[1] = __floats2half2_rn(acc[r][c][2] * d, acc[r][c][3] * d);
        G2[(size_t)gr * (NT / 4) + tx * TN4 + c] = u.f;
      }
    }
  }
}

// ===== fused: gemm1 (unscaled, fp32-in) || passB (packed scatter) =====
__global__ __launch_bounds__(256) void fused_gemm_passB(
    const float* __restrict__ X, const float* __restrict__ W1,
    __half* __restrict__ G, int nrows, int GB,
    const int* __restrict__ ei, int* __restrict__ bfill,
    unsigned int* __restrict__ pairs, int E) {
  if ((int)blockIdx.x < GB) {
    __shared__ float4 Xs[128 * 4];
    __shared__ float4 Ws[16 * 32];
    gemm_body<128, false, false>(X, W1, nullptr, G, nrows, blockIdx.x, Xs, Ws);
  } else {
    __shared__ int hist[256];
    __shared__ int gbase[256];
    int bid = blockIdx.x - GB;
    int t = threadIdx.x;
    hist[t] = 0;
    __syncthreads();
    int d[8], s[8], lp[8], bb[8];
    int base = bid * 2048;
#pragma unroll
    for (int u = 0; u < 8; ++u) {
      int e = base + u * 256 + t;
      if (e < E) {
        d[u] = ei[E + e];
        s[u] = ei[e];
        bb[u] = d[u] >> BSH;
        lp[u] = atomicAdd(&hist[bb[u]], 1);
      } else {
        bb[u] = -1;
      }
    }
    __syncthreads();
    if (hist[t]) gbase[t] = atomicAdd(&bfill[t], hist[t]);
    __syncthreads();
#pragma unroll
    for (int u = 0; u < 8; ++u)
      if (bb[u] >= 0)
        pairs[gbase[bb[u]] + lp[u]] =
            ((unsigned int)(d[u] & (BSZ - 1)) << 17) | (unsigned int)s[u];
  }
}

// passC: per-bucket LDS count/scan/fill (512 threads, packed pairs)
__global__ __launch_bounds__(512) void passC(const unsigned int* __restrict__ pairs,
                                             const int* __restrict__ bstart,
                                             int* __restrict__ rowstart,
                                             int* __restrict__ deg,
                                             float* __restrict__ dinv,
                                             int* __restrict__ csr, int N) {
  __shared__ int hcnt[BSZ];
  __shared__ int lfill[BSZ];
  __shared__ int ss[512];
  __shared__ int lcsr[CAP];
  int b = blockIdx.x;
  int t = threadIdx.x;
  int lo = bstart[b], hi = bstart[b + 1];
  int cnt = hi - lo;
  int nbase = b << BSH;
  hcnt[t] = 0;
  __syncthreads();
  for (int k = lo + t; k < hi; k += 512)
    atomicAdd(&hcnt[(pairs[k] >> 17) & (BSZ - 1)], 1);
  __syncthreads();
  int v = hcnt[t];
  ss[t] = v;
  __syncthreads();
  for (int off = 1; off < 512; off <<= 1) {
    int add = (t >= off) ? ss[t - off] : 0;
    __syncthreads();
    ss[t] += add;
    __syncthreads();
  }
  int ex = ss[t] - v;
  lfill[t] = ex;
  int node = nbase + t;
  if (node < N) {
    rowstart[node] = lo + ex;
    deg[node] = v;
    dinv[node] = rsqrtf((float)(v + 1));
  }
  __syncthreads();
  bool fits = (cnt <= CAP);
  for (int k = lo + t; k < hi; k += 512) {
    unsigned int p = pairs[k];
    int pos = atomicAdd(&lfill[(p >> 17) & (BSZ - 1)], 1);
    int src = (int)(p & 0x1FFFFu);
    if (fits) lcsr[pos] = src;
    else      csr[lo + pos] = src;
  }
  __syncthreads();
  if (fits)
    for (int k = t; k < cnt; k += 512) csr[lo + k] = lcsr[k];
}

// ===== agg128: x2[i] = relu(dinv[i]*(dinv[i]*G[i] + sum dinv[s]*G[s]) + b1) =====
__global__ __launch_bounds__(256) void agg128(
    const __half* __restrict__ G, const int* __restrict__ csr,
    const int* __restrict__ rowstart, const int* __restrict__ deg,
    const float* __restrict__ dinv, const float* __restrict__ bias,
    __half* __restrict__ out, int n) {
  int wid = blockIdx.x * 4 + (threadIdx.x >> 6);
  if (wid >= n) return;
  int i = __builtin_amdgcn_readfirstlane(wid);
  int lane = threadIdx.x & 63;
  const __half2* Gp = (const __half2*)G;
  float di = dinv[i];
  float2 g = __half22float2(Gp[(size_t)i * 64 + lane]);
  float2 a = {di * g.x, di * g.y};   // self-loop (unscaled G)
  int s = rowstart[i];
  int d = deg[i];
  int cnt = d < 64 ? d : 64;
  int myidx = 0;
  if (lane < cnt) myidx = csr[s + lane];
  int k = 0;
  for (; k + 3 < cnt; k += 4) {
    int s0 = __builtin_amdgcn_readfirstlane(__shfl(myidx, k));
    int s1 = __builtin_amdgcn_readfirstlane(__shfl(myidx, k + 1));
    int s2 = __builtin_amdgcn_readfirstlane(__shfl(myidx, k + 2));
    int s3 = __builtin_amdgcn_readfirstlane(__shfl(myidx, k + 3));
    float w0 = dinv[s0], w1 = dinv[s1], w2 = dinv[s2], w3 = dinv[s3];
    float2 v0 = __half22float2(Gp[(size_t)s0 * 64 + lane]);
    float2 v1 = __half22float2(Gp[(size_t)s1 * 64 + lane]);
    float2 v2 = __half22float2(Gp[(size_t)s2 * 64 + lane]);
    float2 v3 = __half22float2(Gp[(size_t)s3 * 64 + lane]);
    a.x = fmaf(w0, v0.x, a.x); a.y = fmaf(w0, v0.y, a.y);
    a.x = fmaf(w1, v1.x, a.x); a.y = fmaf(w1, v1.y, a.y);
    a.x = fmaf(w2, v2.x, a.x); a.y = fmaf(w2, v2.y, a.y);
    a.x = fmaf(w3, v3.x, a.x); a.y = fmaf(w3, v3.y, a.y);
  }
  for (; k < cnt; ++k) {
    int s0 = __builtin_amdgcn_readfirstlane(__shfl(myidx, k));
    float w0 = dinv[s0];
    float2 v0 = __half22float2(Gp[(size_t)s0 * 64 + lane]);
    a.x = fmaf(w0, v0.x, a.x); a.y = fmaf(w0, v0.y, a.y);
  }
  for (int j = s + 64; j < s + d; ++j) {   // degree > 64 tail (rare)
    int s0 = __builtin_amdgcn_readfirstlane(csr[j]);
    float w0 = dinv[s0];
    float2 v0 = __half22float2(Gp[(size_t)s0 * 64 + lane]);
    a.x = fmaf(w0, v0.x, a.x); a.y = fmaf(w0, v0.y, a.y);
  }
  float2 b = ((const float2*)bias)[lane];
  float ox = fmaxf(fmaf(di, a.x, b.x), 0.f);
  float oy = fmaxf(fmaf(di, a.y, b.y), 0.f);
  ((__half2*)out)[(size_t)i * 64 + lane] = __floats2half2_rn(ox, oy);
}

// ===== agg64: out[i] = relu(dinv[i]*(G2[i] + sum G2[s]) + b2), G2 dinv-folded =====
__global__ __launch_bounds__(256) void agg64(
    const __half* __restrict__ G, const int* __restrict__ csr,
    const int* __restrict__ rowstart, const int* __restrict__ deg,
    const float* __restrict__ dinv, const float* __restrict__ bias,
    float* __restrict__ out, int n) {
  int wid = blockIdx.x * 4 + (threadIdx.x >> 6);
  if (wid >= n) return;
  int i = __builtin_amdgcn_readfirstlane(wid);
  int lane = threadIdx.x & 63;
  float a = __half2float(G[(size_t)i * 64 + lane]);  // self (dinv folded in gemm2)
  int s = rowstart[i];
  int d = deg[i];
  int cnt = d < 64 ? d : 64;
  int myidx = 0;
  if (lane < cnt) myidx = csr[s + lane];
  int k = 0;
  for (; k + 3 < cnt; k += 4) {
    int s0 = __builtin_amdgcn_readfirstlane(__shfl(myidx, k));
    int s1 = __builtin_amdgcn_readfirstlane(__shfl(myidx, k + 1));
    int s2 = __builtin_amdgcn_readfirstlane(__shfl(myidx, k + 2));
    int s3 = __builtin_amdgcn_readfirstlane(__shfl(myidx, k + 3));
    float v0 = __half2float(G[(size_t)s0 * 64 + lane]);
    float v1 = __half2float(G[(size_t)s1 * 64 + lane]);
    float v2 = __half2float(G[(size_t)s2 * 64 + lane]);
    float v3 = __half2float(G[(size_t)s3 * 64 + lane]);
    a += (v0 + v1) + (v2 + v3);
  }
  for (; k < cnt; ++k) {
    int s0 = __builtin_amdgcn_readfirstlane(__shfl(myidx, k));
    a += __half2float(G[(size_t)s0 * 64 + lane]);
  }
  for (int j = s + 64; j < s + d; ++j) {
    int s0 = __builtin_amdgcn_readfirstlane(csr[j]);
    a += __half2float(G[(size_t)s0 * 64 + lane]);
  }
  float o = fmaxf(fmaf(dinv[i], a, bias[lane]), 0.f);
  out[(size_t)i * 64 + lane] = o;
}

// gemm2 standalone (fp16 in, dinv-folded out)
__global__ __launch_bounds__(256) void gemm64(const __half* __restrict__ X,
                                              const float* __restrict__ W,
                                              const float* __restrict__ dinv,
                                              __half* __restrict__ G, int nrows) {
  __shared__ float4 Xs[128 * 4];
  __shared__ float4 Ws[16 * 16];
  gemm_body<64, true, true>(X, W, dinv, G, nrows, blockIdx.x, Xs, Ws);
}

// ================= launch =================
extern "C" void kernel_launch(void* const* d_in, const int* in_sizes, int n_in,
                              void* d_out, int out_size, void* d_ws, size_t ws_size,
                              hipStream_t stream) {
  const float* x  = (const float*)d_in[0];
  const int*   ei = (const int*)d_in[1];
  const float* W1 = (const float*)d_in[2];
  const float* b1 = (const float*)d_in[3];
  const float* W2 = (const float*)d_in[4];
  const float* b2 = (const float*)d_in[5];
  float* out = (float*)d_out;

  const int N = in_sizes[0] / 128;
  const int E = in_sizes[1] / 2;
  const int NB = (N + BSZ - 1) >> BSH;   // 196 for N=100k

  char* base = (char*)d_ws;
  size_t off = 0;
  auto alloc = [&](size_t bytes) -> void* {
    void* p = base + off;
    off += (bytes + 255) & ~(size_t)255;
    return p;
  };
  int*          bcount   = (int*)alloc(256 * 4);
  int*          bstart   = (int*)alloc(260 * 4);
  int*          bfill    = (int*)alloc(256 * 4);
  int*          deg      = (int*)alloc((size_t)N * 4);
  int*          rowstart = (int*)alloc((size_t)N * 4);
  float*        dinv     = (float*)alloc((size_t)N * 4);
  int*          csr      = (int*)alloc((size_t)E * 4);
  unsigned int* pairs    = (unsigned int*)alloc((size_t)E * 4);
  __half*       g1       = (__half*)alloc((size_t)N * 128 * 2);  // reused for g2
  __half*       x2       = (__half*)alloc((size_t)N * 128 * 2);

  hipMemsetAsync(bcount, 0, 256 * 4, stream);
  passA<<<512, 256, 0, stream>>>(ei, bcount, E, NB);
  scanB<<<1, 256, 0, stream>>>(bcount, bstart, bfill, NB, E);

  int GB = (N + 127) / 128;            // 782 gemm blocks
  int PB = (E + 2047) / 2048;          // 782 passB blocks
  fused_gemm_passB<<<GB + PB, 256, 0, stream>>>(x, W1, g1, N, GB, ei, bfill, pairs, E);

  passC<<<NB, 512, 0, stream>>>(pairs, bstart, rowstart, deg, dinv, csr, N);

  agg128<<<(N + 3) / 4, 256, 0, stream>>>(g1, csr, rowstart, deg, dinv, b1, x2, N);
  gemm64<<<GB, 256, 0, stream>>>(x2, W2, dinv, g1, N);
  agg64<<<(N + 3) / 4, 256, 0, stream>>>(g1, csr, rowstart, deg, dinv, b2, out, N);
}

// Round 6
// 297.663 us; speedup vs baseline: 1.8535x; 1.0939x over previous
//
#include <hip/hip_runtime.h>
#include <hip/hip_fp16.h>

typedef _Float16 f16x8 __attribute__((ext_vector_type(8)));
typedef float f32x4 __attribute__((ext_vector_type(4)));

// ================= bucketed CSR build =================
#define BSH 9
#define BSZ 512
#define CAP 12288

__global__ __launch_bounds__(256) void passA(const int* __restrict__ ei,
                                             int* __restrict__ bcount, int E, int NB) {
  __shared__ int hist[256];
  int t = threadIdx.x;
  hist[t] = 0;
  __syncthreads();
  for (int e = blockIdx.x * 256 + t; e < E; e += gridDim.x * 256)
    atomicAdd(&hist[ei[E + e] >> BSH], 1);
  __syncthreads();
  if (t < NB && hist[t]) atomicAdd(&bcount[t], hist[t]);
}

__global__ __launch_bounds__(256) void scanB(const int* __restrict__ bcount,
                                             int* __restrict__ bstart,
                                             int* __restrict__ bfill, int NB, int E) {
  __shared__ int s[256];
  int t = threadIdx.x;
  int v = (t < NB) ? bcount[t] : 0;
  s[t] = v;
  __syncthreads();
  for (int off = 1; off < 256; off <<= 1) {
    int add = (t >= off) ? s[t - off] : 0;
    __syncthreads();
    s[t] += add;
    __syncthreads();
  }
  if (t < NB) {
    int ex = s[t] - v;
    bstart[t] = ex;
    bfill[t] = ex;
  }
  if (t == 0) bstart[NB] = E;
}

// ============ MFMA GEMM body: G = (X @ W) [* dinv] -> fp16 ============
template <int NC, int NWC, bool IN_F16, bool SCALE>
__device__ __forceinline__ void gemm_mfma_body(
    const void* __restrict__ Xv, const float* __restrict__ W,
    const float* __restrict__ dinv, _Float16* __restrict__ G, int nrows, int bid,
    _Float16* Bs) {
  int t = threadIdx.x;
  {
    int n = t % NC;
    int kh = (t / NC) * (NC / 2);
    constexpr int NBLK = (NC / 2) / 8;
#pragma unroll
    for (int b = 0; b < NBLK; ++b) {
      f16x8 tmp;
#pragma unroll
      for (int j = 0; j < 8; ++j)
        tmp[j] = (_Float16)W[(size_t)(kh + b * 8 + j) * NC + n];
      *(f16x8*)(&Bs[n * 136 + kh + b * 8]) = tmp;
    }
  }
  __syncthreads();

  int w = t >> 6, lane = t & 63;
  int m = lane & 15, q = lane >> 4;
  int wr = (w / NWC) * 64, wc = (w % NWC) * 64;
  int row0 = bid * ((4 / NWC) * 64);

  f32x4 acc[4][4];
#pragma unroll
  for (int rt = 0; rt < 4; ++rt)
#pragma unroll
    for (int ct = 0; ct < 4; ++ct)
#pragma unroll
      for (int qq = 0; qq < 4; ++qq) acc[rt][ct][qq] = 0.f;

#pragma unroll
  for (int kc = 0; kc < 4; ++kc) {
    int kbase = kc * 32 + q * 8;
    f16x8 af[4];
#pragma unroll
    for (int rt = 0; rt < 4; ++rt) {
      int row = row0 + wr + rt * 16 + m;
      if constexpr (IN_F16) {
        f16x8 a = {0, 0, 0, 0, 0, 0, 0, 0};
        if (row < nrows) a = *(const f16x8*)((const _Float16*)Xv + (size_t)row * 128 + kbase);
        af[rt] = a;
      } else {
        float4 x0 = {0, 0, 0, 0}, x1 = {0, 0, 0, 0};
        if (row < nrows) {
          const float* Xf = (const float*)Xv;
          x0 = *(const float4*)(Xf + (size_t)row * 128 + kbase);
          x1 = *(const float4*)(Xf + (size_t)row * 128 + kbase + 4);
        }
        f16x8 a;
        a[0] = (_Float16)x0.x; a[1] = (_Float16)x0.y;
        a[2] = (_Float16)x0.z; a[3] = (_Float16)x0.w;
        a[4] = (_Float16)x1.x; a[5] = (_Float16)x1.y;
        a[6] = (_Float16)x1.z; a[7] = (_Float16)x1.w;
        af[rt] = a;
      }
    }
    f16x8 bf[4];
#pragma unroll
    for (int ct = 0; ct < 4; ++ct) {
      int n = wc + ct * 16 + m;
      bf[ct] = *(f16x8*)(&Bs[n * 136 + kbase]);
    }
#pragma unroll
    for (int rt = 0; rt < 4; ++rt)
#pragma unroll
      for (int ct = 0; ct < 4; ++ct)
        acc[rt][ct] = __builtin_amdgcn_mfma_f32_16x16x32_f16(af[rt], bf[ct],
                                                             acc[rt][ct], 0, 0, 0);
  }
#pragma unroll
  for (int rt = 0; rt < 4; ++rt) {
#pragma unroll
    for (int r = 0; r < 4; ++r) {
      int row = row0 + wr + rt * 16 + q * 4 + r;
      if (row < nrows) {
        float d = SCALE ? dinv[row] : 1.f;
#pragma unroll
        for (int ct = 0; ct < 4; ++ct) {
          int col = wc + ct * 16 + m;
          G[(size_t)row * NC + col] = (_Float16)(acc[rt][ct][r] * d);
        }
      }
    }
  }
}

// ===== fused: gemm1 (MFMA, unscaled, fp32-in) interleaved with passB =====
__global__ __launch_bounds__(256) void fused_gemm_passB(
    const float* __restrict__ X, const float* __restrict__ W1,
    _Float16* __restrict__ G, int nrows, int GB,
    const int* __restrict__ ei, int* __restrict__ bfill,
    unsigned int* __restrict__ pairs, int E, int PB) {
  __shared__ char smem[128 * 136 * 2];
  int g = blockIdx.x;
  int M2 = 2 * (GB < PB ? GB : PB);
  bool is_gemm;
  int bid;
  if (g < M2) { is_gemm = (g & 1) == 0; bid = g >> 1; }
  else        { is_gemm = (GB > PB);    bid = g - M2 + (GB < PB ? GB : PB); }
  if (is_gemm) {
    gemm_mfma_body<128, 2, false, false>(X, W1, nullptr, G, nrows, bid,
                                         (_Float16*)smem);
  } else {
    int* hist = (int*)smem;
    int* gbase = (int*)(smem + 1024);
    int t = threadIdx.x;
    hist[t] = 0;
    __syncthreads();
    int d[8], s[8], lp[8], bb[8];
    int base = bid * 2048;
#pragma unroll
    for (int u = 0; u < 8; ++u) {
      int e = base + u * 256 + t;
      if (e < E) {
        d[u] = ei[E + e];
        s[u] = ei[e];
        bb[u] = d[u] >> BSH;
        lp[u] = atomicAdd(&hist[bb[u]], 1);
      } else {
        bb[u] = -1;
      }
    }
    __syncthreads();
    if (hist[t]) gbase[t] = atomicAdd(&bfill[t], hist[t]);
    __syncthreads();
#pragma unroll
    for (int u = 0; u < 8; ++u)
      if (bb[u] >= 0)
        pairs[gbase[bb[u]] + lp[u]] =
            ((unsigned int)(d[u] & (BSZ - 1)) << 17) | (unsigned int)s[u];
  }
}

__global__ __launch_bounds__(256) void gemm2_mfma(const _Float16* __restrict__ X,
                                                  const float* __restrict__ W,
                                                  const float* __restrict__ dinv,
                                                  _Float16* __restrict__ G, int nrows) {
  __shared__ _Float16 Bs[64 * 136];
  gemm_mfma_body<64, 1, true, true>(X, W, dinv, G, nrows, blockIdx.x, Bs);
}

// passC: per-bucket LDS count/scan/fill
__global__ __launch_bounds__(512) void passC(const unsigned int* __restrict__ pairs,
                                             const int* __restrict__ bstart,
                                             int* __restrict__ rowstart,
                                             int* __restrict__ deg,
                                             float* __restrict__ dinv,
                                             int* __restrict__ csr, int N) {
  __shared__ int hcnt[BSZ];
  __shared__ int lfill[BSZ];
  __shared__ int ss[512];
  __shared__ int lcsr[CAP];
  int b = blockIdx.x;
  int t = threadIdx.x;
  int lo = bstart[b], hi = bstart[b + 1];
  int cnt = hi - lo;
  int nbase = b << BSH;
  hcnt[t] = 0;
  __syncthreads();
  for (int k = lo + t; k < hi; k += 512)
    atomicAdd(&hcnt[(pairs[k] >> 17) & (BSZ - 1)], 1);
  __syncthreads();
  int v = hcnt[t];
  ss[t] = v;
  __syncthreads();
  for (int off = 1; off < 512; off <<= 1) {
    int add = (t >= off) ? ss[t - off] : 0;
    __syncthreads();
    ss[t] += add;
    __syncthreads();
  }
  int ex = ss[t] - v;
  lfill[t] = ex;
  int node = nbase + t;
  if (node < N) {
    rowstart[node] = lo + ex;
    deg[node] = v;
    dinv[node] = rsqrtf((float)(v + 1));
  }
  __syncthreads();
  bool fits = (cnt <= CAP);
  for (int k = lo + t; k < hi; k += 512) {
    unsigned int p = pairs[k];
    int pos = atomicAdd(&lfill[(p >> 17) & (BSZ - 1)], 1);
    int src = (int)(p & 0x1FFFFu);
    if (fits) lcsr[pos] = src;
    else      csr[lo + pos] = src;
  }
  __syncthreads();
  if (fits)
    for (int k = t; k < cnt; k += 512) csr[lo + k] = lcsr[k];
}

// ===== agg128 (round-4 proven): x2[i]=relu(di*(di*G[i]+sum dinv[s]*G[s])+b1) =====
__global__ __launch_bounds__(256) void agg128(
    const __half* __restrict__ G, const int* __restrict__ csr,
    const int* __restrict__ rowstart, const int* __restrict__ deg,
    const float* __restrict__ dinv, const float* __restrict__ bias,
    __half* __restrict__ out, int n) {
  int wid = blockIdx.x * 4 + (threadIdx.x >> 6);
  if (wid >= n) return;
  int i = __builtin_amdgcn_readfirstlane(wid);
  int lane = threadIdx.x & 63;
  const __half2* Gp = (const __half2*)G;
  float di = dinv[i];
  float2 g = __half22float2(Gp[(size_t)i * 64 + lane]);
  float2 a = {di * g.x, di * g.y};
  int s = rowstart[i];
  int d = deg[i];
  int cnt = d < 64 ? d : 64;
  int myidx = 0;
  if (lane < cnt) myidx = csr[s + lane];
  int k = 0;
  for (; k + 3 < cnt; k += 4) {
    int s0 = __builtin_amdgcn_readfirstlane(__shfl(myidx, k));
    int s1 = __builtin_amdgcn_readfirstlane(__shfl(myidx, k + 1));
    int s2 = __builtin_amdgcn_readfirstlane(__shfl(myidx, k + 2));
    int s3 = __builtin_amdgcn_readfirstlane(__shfl(myidx, k + 3));
    float w0 = dinv[s0], w1 = dinv[s1], w2 = dinv[s2], w3 = dinv[s3];
    float2 v0 = __half22float2(Gp[(size_t)s0 * 64 + lane]);
    float2 v1 = __half22float2(Gp[(size_t)s1 * 64 + lane]);
    float2 v2 = __half22float2(Gp[(size_t)s2 * 64 + lane]);
    float2 v3 = __half22float2(Gp[(size_t)s3 * 64 + lane]);
    a.x = fmaf(w0, v0.x, a.x); a.y = fmaf(w0, v0.y, a.y);
    a.x = fmaf(w1, v1.x, a.x); a.y = fmaf(w1, v1.y, a.y);
    a.x = fmaf(w2, v2.x, a.x); a.y = fmaf(w2, v2.y, a.y);
    a.x = fmaf(w3, v3.x, a.x); a.y = fmaf(w3, v3.y, a.y);
  }
  for (; k < cnt; ++k) {
    int s0 = __builtin_amdgcn_readfirstlane(__shfl(myidx, k));
    float w0 = dinv[s0];
    float2 v0 = __half22float2(Gp[(size_t)s0 * 64 + lane]);
    a.x = fmaf(w0, v0.x, a.x); a.y = fmaf(w0, v0.y, a.y);
  }
  for (int j = s + 64; j < s + d; ++j) {
    int s0 = __builtin_amdgcn_readfirstlane(csr[j]);
    float w0 = dinv[s0];
    float2 v0 = __half22float2(Gp[(size_t)s0 * 64 + lane]);
    a.x = fmaf(w0, v0.x, a.x); a.y = fmaf(w0, v0.y, a.y);
  }
  float2 b = ((const float2*)bias)[lane];
  float ox = fmaxf(fmaf(di, a.x, b.x), 0.f);
  float oy = fmaxf(fmaf(di, a.y, b.y), 0.f);
  ((__half2*)out)[(size_t)i * 64 + lane] = __floats2half2_rn(ox, oy);
}

// ===== agg64 (round-4 proven): out[i]=relu(di*(G2[i]+sum G2[s])+b2) =====
__global__ __launch_bounds__(256) void agg64(
    const __half* __restrict__ G, const int* __restrict__ csr,
    const int* __restrict__ rowstart, const int* __restrict__ deg,
    const float* __restrict__ dinv, const float* __restrict__ bias,
    float* __restrict__ out, int n) {
  int wid = blockIdx.x * 4 + (threadIdx.x >> 6);
  if (wid >= n) return;
  int i = __builtin_amdgcn_readfirstlane(wid);
  int lane = threadIdx.x & 63;
  float a = __half2float(G[(size_t)i * 64 + lane]);
  int s = rowstart[i];
  int d = deg[i];
  int cnt = d < 64 ? d : 64;
  int myidx = 0;
  if (lane < cnt) myidx = csr[s + lane];
  int k = 0;
  for (; k + 3 < cnt; k += 4) {
    int s0 = __builtin_amdgcn_readfirstlane(__shfl(myidx, k));
    int s1 = __builtin_amdgcn_readfirstlane(__shfl(myidx, k + 1));
    int s2 = __builtin_amdgcn_readfirstlane(__shfl(myidx, k + 2));
    int s3 = __builtin_amdgcn_readfirstlane(__shfl(myidx, k + 3));
    float v0 = __half2float(G[(size_t)s0 * 64 + lane]);
    float v1 = __half2float(G[(size_t)s1 * 64 + lane]);
    float v2 = __half2float(G[(size_t)s2 * 64 + lane]);
    float v3 = __half2float(G[(size_t)s3 * 64 + lane]);
    a += (v0 + v1) + (v2 + v3);
  }
  for (; k < cnt; ++k) {
    int s0 = __builtin_amdgcn_readfirstlane(__shfl(myidx, k));
    a += __half2float(G[(size_t)s0 * 64 + lane]);
  }
  for (int j = s + 64; j < s + d; ++j) {
    int s0 = __builtin_amdgcn_readfirstlane(csr[j]);
    a += __half2float(G[(size_t)s0 * 64 + lane]);
  }
  float o = fmaxf(fmaf(dinv[i], a, bias[lane]), 0.f);
  out[(size_t)i * 64 + lane] = o;
}

// ================= launch =================
extern "C" void kernel_launch(void* const* d_in, const int* in_sizes, int n_in,
                              void* d_out, int out_size, void* d_ws, size_t ws_size,
                              hipStream_t stream) {
  const float* x  = (const float*)d_in[0];
  const int*   ei = (const int*)d_in[1];
  const float* W1 = (const float*)d_in[2];
  const float* b1 = (const float*)d_in[3];
  const float* W2 = (const float*)d_in[4];
  const float* b2 = (const float*)d_in[5];
  float* out = (float*)d_out;

  const int N = in_sizes[0] / 128;
  const int E = in_sizes[1] / 2;
  const int NB = (N + BSZ - 1) >> BSH;

  char* base = (char*)d_ws;
  size_t off = 0;
  auto alloc = [&](size_t bytes) -> void* {
    void* p = base + off;
    off += (bytes + 255) & ~(size_t)255;
    return p;
  };
  int*          bcount   = (int*)alloc(256 * 4);
  int*          bstart   = (int*)alloc(260 * 4);
  int*          bfill    = (int*)alloc(256 * 4);
  int*          deg      = (int*)alloc((size_t)N * 4);
  int*          rowstart = (int*)alloc((size_t)N * 4);
  float*        dinv     = (float*)alloc((size_t)N * 4);
  int*          csr      = (int*)alloc((size_t)E * 4);
  unsigned int* pairs    = (unsigned int*)alloc((size_t)E * 4);
  __half*       g1       = (__half*)alloc((size_t)N * 128 * 2);  // reused for g2
  __half*       x2       = (__half*)alloc((size_t)N * 128 * 2);

  hipMemsetAsync(bcount, 0, 256 * 4, stream);
  passA<<<512, 256, 0, stream>>>(ei, bcount, E, NB);
  scanB<<<1, 256, 0, stream>>>(bcount, bstart, bfill, NB, E);

  int GB = (N + 127) / 128;
  int PB = (E + 2047) / 2048;
  fused_gemm_passB<<<GB + PB, 256, 0, stream>>>(x, W1, (_Float16*)g1, N, GB, ei,
                                                bfill, pairs, E, PB);
  passC<<<NB, 512, 0, stream>>>(pairs, bstart, rowstart, deg, dinv, csr, N);

  agg128<<<(N + 3) / 4, 256, 0, stream>>>(g1, csr, rowstart, deg, dinv, b1, x2, N);
  int G2B = (N + 255) / 256;
  gemm2_mfma<<<G2B, 256, 0, stream>>>((const _Float16*)x2, W2, dinv,
                                      (_Float16*)g1, N);
  agg64<<<(N + 3) / 4, 256, 0, stream>>>(g1, csr, rowstart, deg, dinv, b2, out, N);
}